// Round 10
// baseline (22.570 us; speedup 1.0000x reference)
//
#include <hip/hip_runtime.h>

#define NPART   2048
#define NCOMP   8192
#define NBATCH  8
#define THRESH  0.05f
#define FLTMAX  3.4028235e38f

#define SLOTS   32                        // point-slots per block
#define SEGS    32                        // partial segments (tid>>5)
#define SEGLEN  (NPART / SEGS)            // 64 partials per segment
#define ITERS   (SEGLEN / 4)              // 16 iterations of 4 partials
#define PPT     4                         // completed points per thread
#define PTSBLK  (SLOTS * PPT)             // 128 completed points per block
#define BLKSPB  (NCOMP / PTSBLK)          // 64 blocks per batch
#define GRID    (NBATCH * BLKSPB)         // 512 blocks -> 2 blocks/CU, 8 waves/SIMD
#define WAVES   16

__global__ __launch_bounds__(1024, 8) void pml_main(
    const float* __restrict__ completed,
    const float* __restrict__ partial,
    float2* __restrict__ slots_out)
{
    const int tid   = threadIdx.x;
    const int lane  = tid & 63;
    const int slot  = tid & (SLOTS - 1);
    const int seg   = tid >> 5;              // 0..31; half-wave uniform
    const int wave  = tid >> 6;
    const int batch = blockIdx.x >> 6;
    const int blkb  = blockIdx.x & (BLKSPB - 1);

    __shared__ float smin[PTSBLK][WAVES + 1]; // ~8.7 KB, pitch 17 -> 2-way (free)
    __shared__ float sc2[PTSBLK];
    __shared__ float        rs[PTSBLK / 64];
    __shared__ unsigned int rc[PTSBLK / 64];

    // ---- this thread's 4 completed points (stride-32 -> coalesced) ----
    const float* cb = completed + ((size_t)batch * NCOMP + (size_t)blkb * PTSBLK) * 3;
    float nx[PPT], ny[PPT], nz[PPT], c2[PPT];
    #pragma unroll
    for (int k = 0; k < PPT; ++k) {
        int p = slot + k * SLOTS;
        float x = cb[3 * p + 0];
        float y = cb[3 * p + 1];
        float z = cb[3 * p + 2];
        nx[k] = -2.0f * x;
        ny[k] = -2.0f * y;
        nz[k] = -2.0f * z;
        c2[k] = fmaf(x, x, fmaf(y, y, z * z));
    }

    // ---- scan this segment's 64 partials straight from global/L1 ----
    // 24 KB/batch sits in L1/L2; half-wave-uniform addresses coalesce to 2
    // lines per dwordx4. Manual 2-deep rotation keeps 3 loads in flight so
    // waits are counted vmcnt(N), not vmcnt(0) serial.
    const float4* pv = reinterpret_cast<const float4*>(
        partial + ((size_t)batch * NPART + (size_t)seg * SEGLEN) * 3);

    float acc[PPT];
    #pragma unroll
    for (int k = 0; k < PPT; ++k) acc[k] = FLTMAX;

    float4 r0 = pv[0], r1 = pv[1], r2 = pv[2];
    for (int i = 0; i < ITERS; ++i) {
        const int nxt = 3 * ((i + 1) & (ITERS - 1));   // wraps to 0 on last iter
        float4 n0 = pv[nxt + 0];
        float4 n1 = pv[nxt + 1];
        float4 n2 = pv[nxt + 2];
        // r0 = p0x p0y p0z p1x ; r1 = p1y p1z p2x p2y ; r2 = p2z p3x p3y p3z
        float p0w = fmaf(r0.x, r0.x, fmaf(r0.y, r0.y, r0.z * r0.z));
        float p1w = fmaf(r0.w, r0.w, fmaf(r1.x, r1.x, r1.y * r1.y));
        float p2w = fmaf(r1.z, r1.z, fmaf(r1.w, r1.w, r2.x * r2.x));
        float p3w = fmaf(r2.y, r2.y, fmaf(r2.z, r2.z, r2.w * r2.w));
        #pragma unroll
        for (int k = 0; k < PPT; ++k) {
            float t0 = fmaf(r0.x, nx[k], fmaf(r0.y, ny[k], fmaf(r0.z, nz[k], p0w)));
            float t1 = fmaf(r0.w, nx[k], fmaf(r1.x, ny[k], fmaf(r1.y, nz[k], p1w)));
            float t2 = fmaf(r1.z, nx[k], fmaf(r1.w, ny[k], fmaf(r2.x, nz[k], p2w)));
            float t3 = fmaf(r2.y, nx[k], fmaf(r2.z, ny[k], fmaf(r2.w, nz[k], p3w)));
            // fuses to 2x v_min3_f32; 4 independent chains across k
            acc[k] = fminf(fminf(fminf(fminf(acc[k], t0), t1), t2), t3);
        }
        r0 = n0; r1 = n1; r2 = n2;
    }

    // ---- fold the wave's seg pair via xor-32 shuffle, one LDS write ----
    #pragma unroll
    for (int k = 0; k < PPT; ++k) {
        float t = fminf(acc[k], __int_as_float(
            __shfl_xor(__float_as_int(acc[k]), 32, 64)));
        int p = slot + k * SLOTS;
        if (lane < 32) {
            smin[p][wave] = t;               // banks (17p+w)%32: 2-way, free
            if (wave == 0) sc2[p] = c2[k];
        }
    }
    __syncthreads();

    // ---- combine 16 wave-minima per point, mask, block-reduce ----
    float        v = 0.0f;
    unsigned int c = 0u;
    if (tid < PTSBLK) {
        float t = smin[tid][0];
        #pragma unroll
        for (int g = 1; g < WAVES; ++g) t = fminf(t, smin[tid][g]);
        float m = fmaxf(sc2[tid] + t, 0.0f);
        if (m < THRESH) { v = m; c = 1u; }
        #pragma unroll
        for (int off = 32; off >= 1; off >>= 1) {
            v += __shfl_down(v, off, 64);
            c += __shfl_down(c, off, 64);
        }
        if ((tid & 63) == 0) { rs[tid >> 6] = v; rc[tid >> 6] = c; }
    }
    __syncthreads();
    if (tid == 0) {
        float        bs = 0.0f;
        unsigned int bc = 0u;
        #pragma unroll
        for (int w = 0; w < PTSBLK / 64; ++w) { bs += rs[w]; bc += rc[w]; }
        // plain store to a private slot: no atomics, no fence, no ticket
        slots_out[blockIdx.x] = make_float2(bs, (float)bc);
    }
}

__global__ __launch_bounds__(256) void pml_fin(
    const float2* __restrict__ slots_in,
    float* __restrict__ out)
{
    const int tid = threadIdx.x;
    float2 a = slots_in[tid];                // GRID == 512 == 2 x blockDim
    float2 b = slots_in[tid + 256];
    float s = a.x + b.x;
    float c = a.y + b.y;
    #pragma unroll
    for (int off = 32; off >= 1; off >>= 1) {
        s += __shfl_down(s, off, 64);
        c += __shfl_down(c, off, 64);
    }
    __shared__ float ss[4], sc[4];
    if ((tid & 63) == 0) { ss[tid >> 6] = s; sc[tid >> 6] = c; }
    __syncthreads();
    if (tid == 0) {
        float s2 = ss[0] + ss[1] + ss[2] + ss[3];
        float c2 = sc[0] + sc[1] + sc[2] + sc[3];
        *out = (c2 > 0.0f) ? (s2 / (c2 + 1e-6f)) : 0.0f;   // WEIGHT = 1.0
    }
}

extern "C" void kernel_launch(void* const* d_in, const int* in_sizes, int n_in,
                              void* d_out, int out_size, void* d_ws, size_t ws_size,
                              hipStream_t stream) {
    const float* completed = (const float*)d_in[0];  // (8, 8192, 3) f32
    const float* partial   = (const float*)d_in[1];  // (8, 2048, 3) f32
    float* out = (float*)d_out;
    float2* slots = (float2*)d_ws;                   // 512 slots, all written
                                                     // before fin reads them:
                                                     // no memset node needed

    pml_main<<<dim3(GRID), dim3(1024), 0, stream>>>(completed, partial, slots);
    pml_fin<<<dim3(1), dim3(256), 0, stream>>>(slots, out);
}